// Round 8
// baseline (2538.035 us; speedup 1.0000x reference)
//
#include <hip/hip_runtime.h>
#include <hip/hip_cooperative_groups.h>
#include <math.h>

namespace cg = cooperative_groups;

#define HH 512
#define WW 512
#define BB 8
#define NPIX (HH*WW)
#define NTOT (BB*NPIX)
#define ITER 50

// ---------- persistent kernel geometry ----------
#define PBLK 256            // 8 batches x 32 stripes, 1 block/CU (cooperative)
#define PTHR 512
#define SROWS 16            // image rows per stripe
#define NSTR 32             // stripes per batch
#define PADW 520            // u LDS row stride (2-col zero pad each side + pad)
#define ULDS_F (20*PADW)    // u: rows i0-2..i0+17
#define QLDS_F (17*512)     // q: rows i0-1..i0+15
#define SHLDS_F (20*512)    // h-pass intermediate
#define LDS_FLOATS (ULDS_F + QLDS_F + SHLDS_F)
#define LDS_BYTES (LDS_FLOATS*4)

// Gaussian 5x5 (sigma=5)
constexpr double W0d = 0.92311634638663587;
constexpr double W1d = 0.98019867330675525;
constexpr double SUM1D = 1.0 + 2.0*(W0d + W1d);
constexpr float  INV_NORM = (float)(1.0/(SUM1D*SUM1D + 1e-15));
constexpr float  W0f = (float)W0d;
constexpr float  W1f = (float)W1d;
constexpr float  S1f = (float)SUM1D;

__device__ __forceinline__ float sigmoidf(float x) { return 1.0f / (1.0f + expf(-x)); }

__device__ __forceinline__ float edge1d(int v) {
    float r = S1f;
    if (v == 0 || v == HH - 1) r = S1f - W0f - W1f;
    else if (v == 1 || v == HH - 2) r = S1f - W0f;
    return r;
}

__device__ __forceinline__ void evalF(float uc, float ud, float ur, float qv,
                                      float dx, float dy,
                                      float cossin, float bsin, float asin_,
                                      float& a, float& bv, float& qn) {
    float Tx = -dx * cossin + dy * bsin;
    float Ty =  dy * cossin - dx * asin_;
    const float rn = 1.0f / (sqrtf(Tx * Tx + Ty * Ty) + 1e-10f);
    Tx *= rn; Ty *= rn;
    qn = qv - ((ud - uc) * Tx + (ur - uc) * Ty);
    a  = Tx * qn;
    bv = Ty * qn;
}

// ================= persistent cooperative kernel =================
__global__ __launch_bounds__(PTHR, 2) void persist_kernel(
    const float* __restrict__ o, float* __restrict__ out,
    float* __restrict__ haloU,   // [2][PBLK][4][512]
    float* __restrict__ haloQ,   // [2][PBLK][512]
    float* __restrict__ part)    // [2][8][NSTR][8]
{
    extern __shared__ float lds[];
    float* U  = lds;                      // [20][PADW] img row i0-2+r, img col c -> [r][c+2]
    float* Q  = lds + ULDS_F;             // [17][512]  img row i0-1+r
    float* SH = lds + ULDS_F + QLDS_F;    // [20][512]
    __shared__ float sc[5];
    __shared__ float smP[8][6];

    const int blk    = blockIdx.x;
    const int b      = blk & 7;
    const int stripe = blk >> 3;
    const int i0     = stripe * SROWS;
    const int t      = threadIdx.x;

    const float* ob   = o   + (size_t)b * NPIX;
    float*       outb = out + (size_t)b * NPIX;

    cg::grid_group grid = cg::this_grid();

    const int r_own = t >> 5;          // 0..15
    const int seg   = t & 31;
    const int c0    = seg * 16;
    const int i     = i0 + r_own;
    const int ru    = r_own + 2;
    const int rq    = r_own + 1;

    // ---------- init: u0 = sigmoid(o) (zeros OOB), q = 0, col pads = 0 ----------
    for (int e = t; e < 20 * 32; e += PTHR) {
        const int r = e >> 5, sg = e & 31;
        const int ii = i0 - 2 + r;
        const int cc = sg * 16;
        #pragma unroll
        for (int g = 0; g < 4; g++) {
            float4 res = make_float4(0.f, 0.f, 0.f, 0.f);
            if (ii >= 0 && ii < HH) {
                const float4 ov = *(const float4*)(ob + ii * WW + cc + 4 * g);
                res = make_float4(sigmoidf(ov.x), sigmoidf(ov.y), sigmoidf(ov.z), sigmoidf(ov.w));
            }
            *(float4*)&U[r * PADW + 2 + cc + 4 * g] = res;
        }
        if (sg == 0) {
            U[r * PADW + 0] = 0.f; U[r * PADW + 1] = 0.f;
            U[r * PADW + 514] = 0.f; U[r * PADW + 515] = 0.f;
        }
    }
    for (int e = t; e < 17 * 128; e += PTHR)
        *(float4*)&Q[e * 4] = make_float4(0.f, 0.f, 0.f, 0.f);
    __syncthreads();

    // ---------- iter-0 partials from own rows ----------
    {
        const float x = (float)(i + 1);
        float s0 = 0.f, sy = 0.f, syy = 0.f;
        #pragma unroll
        for (int m = 0; m < 16; m++) {
            const float uu = U[ru * PADW + 2 + c0 + m];
            const float y = (float)(c0 + m + 1);
            s0 += uu; sy += uu * y; syy += uu * y * y;
        }
        float v[6] = {s0, x * s0, sy, x * sy, x * x * s0, syy};
        #pragma unroll
        for (int c = 0; c < 6; c++) {
            #pragma unroll
            for (int off = 32; off > 0; off >>= 1) v[c] += __shfl_down(v[c], off, 64);
        }
        const int lane = t & 63, wv = t >> 6;
        if (lane == 0) {
            #pragma unroll
            for (int c = 0; c < 6; c++) smP[wv][c] = v[c];
        }
        __syncthreads();
        if (t == 0) {
            float r6[6];
            #pragma unroll
            for (int c = 0; c < 6; c++)
                r6[c] = smP[0][c]+smP[1][c]+smP[2][c]+smP[3][c]+smP[4][c]+smP[5][c]+smP[6][c]+smP[7][c];
            float* dst = part + ((size_t)(0 * 8 + b) * NSTR + stripe) * 8;
            *(float4*)dst       = make_float4(r6[0], r6[1], r6[2], r6[3]);
            *(float4*)(dst + 4) = make_float4(r6[4], r6[5], 0.f, 0.f);
        }
    }
    grid.sync();
    // scalars from parity 0
    if (t < 64) {
        const float* pb = part + (size_t)(0 * 8 + b) * NSTR * 8;
        double v[6] = {0, 0, 0, 0, 0, 0};
        if (t < 32) {
            const float4 a  = *(const float4*)(pb + t * 8);
            const float4 b4 = *(const float4*)(pb + t * 8 + 4);
            v[0] = a.x; v[1] = a.y; v[2] = a.z; v[3] = a.w; v[4] = b4.x; v[5] = b4.y;
        }
        #pragma unroll
        for (int off = 16; off > 0; off >>= 1) {
            #pragma unroll
            for (int c = 0; c < 6; c++) v[c] += __shfl_down(v[c], off, 64);
        }
        if (t == 0) {
            const double s = v[0], inv = 1.0 / s;
            const double cx = v[1] * inv, cy = v[2] * inv;
            sc[0] = (float)cx; sc[1] = (float)cy;
            sc[2] = (float)(v[3] * inv - cx * cy);
            sc[3] = (float)(v[4] * inv - cx * cx);
            sc[4] = (float)(v[5] * inv - cy * cy);
        }
    }
    __syncthreads();

    // ---------- main loop ----------
    for (int k = 0; k < ITER; k++) {
        // A: horizontal gaussian pass, 20 rows
        for (int e = t; e < 20 * 32; e += PTHR) {
            const int r = e >> 5, cc = (e & 31) * 16;
            float w[20];
            #pragma unroll
            for (int g = 0; g < 5; g++) {
                const float4 a = *(const float4*)&U[r * PADW + cc + 4 * g];
                w[4*g] = a.x; w[4*g+1] = a.y; w[4*g+2] = a.z; w[4*g+3] = a.w;
            }
            #pragma unroll
            for (int g = 0; g < 4; g++) {
                float4 h;
                h.x = W0f*w[4*g+0] + W1f*w[4*g+1] + w[4*g+2] + W1f*w[4*g+3] + W0f*w[4*g+4];
                h.y = W0f*w[4*g+1] + W1f*w[4*g+2] + w[4*g+3] + W1f*w[4*g+4] + W0f*w[4*g+5];
                h.z = W0f*w[4*g+2] + W1f*w[4*g+3] + w[4*g+4] + W1f*w[4*g+5] + W0f*w[4*g+6];
                h.w = W0f*w[4*g+3] + W1f*w[4*g+4] + w[4*g+5] + W1f*w[4*g+6] + W0f*w[4*g+7];
                *(float4*)&SH[r * 512 + cc + 4 * g] = h;
            }
        }
        __syncthreads();

        // B: update own 16 px
        const float cxf = sc[0], cyf = sc[1], cossin = sc[2], bsin = sc[3], asin_ = sc[4];
        const float dx  = (float)(i + 1) - cxf;
        const float dxu = (float)i - cxf;
        const bool  igt0 = (i > 0);
        const float Ri = edge1d(i);

        float Wr[20], Wu[20], Wd[20];
        #pragma unroll
        for (int g = 0; g < 5; g++) {
            const float4 a = *(const float4*)&U[ru * PADW + c0 + 4 * g];
            const float4 u4 = *(const float4*)&U[(ru - 1) * PADW + c0 + 4 * g];
            const float4 d4 = *(const float4*)&U[(ru + 1) * PADW + c0 + 4 * g];
            Wr[4*g] = a.x;  Wr[4*g+1] = a.y;  Wr[4*g+2] = a.z;  Wr[4*g+3] = a.w;
            Wu[4*g] = u4.x; Wu[4*g+1] = u4.y; Wu[4*g+2] = u4.z; Wu[4*g+3] = u4.w;
            Wd[4*g] = d4.x; Wd[4*g+1] = d4.y; Wd[4*g+2] = d4.z; Wd[4*g+3] = d4.w;
        }
        const float ql = (c0 > 0) ? Q[rq * 512 + c0 - 1] : 0.f;

        float bprev;
        {
            float al, bl, qnl;
            evalF(Wr[1], Wd[1], Wr[2], ql, dx, (float)c0 - cyf, cossin, bsin, asin_, al, bl, qnl);
            bprev = (c0 > 0) ? bl : 0.f;
        }

        float un16[16], qn16[16];
        float s0 = 0.f, sy = 0.f, syy = 0.f;
        const int lastFlag = (k == ITER - 1);

        #pragma unroll
        for (int g = 0; g < 4; g++) {
            const float4 qc4 = *(const float4*)&Q[rq * 512 + c0 + 4 * g];
            const float4 qu4 = *(const float4*)&Q[(rq - 1) * 512 + c0 + 4 * g];
            const float4 o4  = *(const float4*)(ob + i * WW + c0 + 4 * g);
            const float4 r0 = *(const float4*)&SH[(r_own + 0) * 512 + c0 + 4 * g];
            const float4 r1 = *(const float4*)&SH[(r_own + 1) * 512 + c0 + 4 * g];
            const float4 r2 = *(const float4*)&SH[(r_own + 2) * 512 + c0 + 4 * g];
            const float4 r3 = *(const float4*)&SH[(r_own + 3) * 512 + c0 + 4 * g];
            const float4 r4 = *(const float4*)&SH[(r_own + 4) * 512 + c0 + 4 * g];
            const float cU[4] = {
                W0f*r0.x + W1f*r1.x + r2.x + W1f*r3.x + W0f*r4.x,
                W0f*r0.y + W1f*r1.y + r2.y + W1f*r3.y + W0f*r4.y,
                W0f*r0.z + W1f*r1.z + r2.z + W1f*r3.z + W0f*r4.z,
                W0f*r0.w + W1f*r1.w + r2.w + W1f*r3.w + W0f*r4.w };
            const float qcv[4] = {qc4.x, qc4.y, qc4.z, qc4.w};
            const float quv[4] = {qu4.x, qu4.y, qu4.z, qu4.w};
            const float ov4[4] = {o4.x, o4.y, o4.z, o4.w};
            float t4[4];
            #pragma unroll
            for (int mm = 0; mm < 4; mm++) {
                const int m = 4 * g + mm;
                const int j = c0 + m;
                const float dy = (float)(j + 1) - cyf;
                float ac, bc, qn;
                evalF(Wr[m + 2], Wd[m + 2], Wr[m + 3], qcv[mm], dx, dy, cossin, bsin, asin_, ac, bc, qn);
                float au, bud, qud;
                evalF(Wu[m + 2], Wr[m + 2], Wu[m + 3], quv[mm], dxu, dy, cossin, bsin, asin_, au, bud, qud);
                au = igt0 ? au : 0.f;
                const float p  = INV_NORM * (Ri * edge1d(j) - 2.0f * cU[mm]);
                const float Tq = ac + bc - au - bprev;
                const float tt = ov4[mm] - p - Tq;
                const float un = sigmoidf(tt);
                un16[m] = un; qn16[m] = qn; t4[mm] = tt;
                bprev = bc;
                const float y = (float)(j + 1);
                s0 += un; sy += un * y; syy += un * y * y;
            }
            if (lastFlag)
                *(float4*)&outb[i * WW + c0 + 4 * g] = make_float4(t4[0], t4[1], t4[2], t4[3]);
        }
        __syncthreads();   // all reads of old u/q/SH done

        // C: write back LDS state + halos + partials
        #pragma unroll
        for (int g = 0; g < 4; g++) {
            *(float4*)&U[ru * PADW + 2 + c0 + 4 * g] =
                make_float4(un16[4*g], un16[4*g+1], un16[4*g+2], un16[4*g+3]);
            *(float4*)&Q[rq * 512 + c0 + 4 * g] =
                make_float4(qn16[4*g], qn16[4*g+1], qn16[4*g+2], qn16[4*g+3]);
        }
        const int pn = (k + 1) & 1;
        float* hu = haloU + ((size_t)pn * PBLK + blk) * 4 * 512;
        if (r_own < 2) {
            #pragma unroll
            for (int g = 0; g < 4; g++)
                *(float4*)&hu[r_own * 512 + c0 + 4 * g] =
                    make_float4(un16[4*g], un16[4*g+1], un16[4*g+2], un16[4*g+3]);
        } else if (r_own >= 14) {
            #pragma unroll
            for (int g = 0; g < 4; g++)
                *(float4*)&hu[(r_own - 12) * 512 + c0 + 4 * g] =
                    make_float4(un16[4*g], un16[4*g+1], un16[4*g+2], un16[4*g+3]);
        }
        if (r_own == 15) {
            float* hq = haloQ + ((size_t)pn * PBLK + blk) * 512;
            #pragma unroll
            for (int g = 0; g < 4; g++)
                *(float4*)&hq[c0 + 4 * g] =
                    make_float4(qn16[4*g], qn16[4*g+1], qn16[4*g+2], qn16[4*g+3]);
        }
        {
            const float x = (float)(i + 1);
            float v[6] = {s0, x * s0, sy, x * sy, x * x * s0, syy};
            #pragma unroll
            for (int c = 0; c < 6; c++) {
                #pragma unroll
                for (int off = 32; off > 0; off >>= 1) v[c] += __shfl_down(v[c], off, 64);
            }
            const int lane = t & 63, wv = t >> 6;
            if (lane == 0) {
                #pragma unroll
                for (int c = 0; c < 6; c++) smP[wv][c] = v[c];
            }
            __syncthreads();
            if (t == 0) {
                float r6[6];
                #pragma unroll
                for (int c = 0; c < 6; c++)
                    r6[c] = smP[0][c]+smP[1][c]+smP[2][c]+smP[3][c]+smP[4][c]+smP[5][c]+smP[6][c]+smP[7][c];
                float* dst = part + ((size_t)(pn * 8 + b) * NSTR + stripe) * 8;
                *(float4*)dst       = make_float4(r6[0], r6[1], r6[2], r6[3]);
                *(float4*)(dst + 4) = make_float4(r6[4], r6[5], 0.f, 0.f);
            }
        }
        if (lastFlag) break;

        grid.sync();

        // D: halo in + scalar finalize
        if (t < 128) {
            const int hr = t >> 5, sg = t & 31;
            const int cc = sg * 16;
            const bool top = (hr < 2);
            const bool valid = top ? (stripe > 0) : (stripe < NSTR - 1);
            const int srcBlk  = top ? (blk - 8) : (blk + 8);
            const int srcSlot = top ? (2 + hr) : (hr - 2);
            const int dstRow  = top ? hr : (16 + hr);
            #pragma unroll
            for (int g = 0; g < 4; g++) {
                float4 vv = make_float4(0.f, 0.f, 0.f, 0.f);
                if (valid)
                    vv = *(const float4*)(haloU + ((size_t)pn * PBLK + srcBlk) * 4 * 512
                                          + srcSlot * 512 + cc + 4 * g);
                *(float4*)&U[dstRow * PADW + 2 + cc + 4 * g] = vv;
            }
        } else if (t < 160) {
            const int sg = t - 128;
            const int cc = sg * 16;
            #pragma unroll
            for (int g = 0; g < 4; g++) {
                float4 vv = make_float4(0.f, 0.f, 0.f, 0.f);
                if (stripe > 0)
                    vv = *(const float4*)(haloQ + ((size_t)pn * PBLK + (blk - 8)) * 512 + cc + 4 * g);
                *(float4*)&Q[cc + 4 * g] = vv;
            }
        } else if (t >= 192 && t < 256) {
            const int l = t - 192;
            const float* pb = part + (size_t)(pn * 8 + b) * NSTR * 8;
            double v[6] = {0, 0, 0, 0, 0, 0};
            if (l < 32) {
                const float4 a  = *(const float4*)(pb + l * 8);
                const float4 b4 = *(const float4*)(pb + l * 8 + 4);
                v[0] = a.x; v[1] = a.y; v[2] = a.z; v[3] = a.w; v[4] = b4.x; v[5] = b4.y;
            }
            #pragma unroll
            for (int off = 16; off > 0; off >>= 1) {
                #pragma unroll
                for (int c = 0; c < 6; c++) v[c] += __shfl_down(v[c], off, 64);
            }
            if (l == 0) {
                const double s = v[0], inv = 1.0 / s;
                const double cx = v[1] * inv, cy = v[2] * inv;
                sc[0] = (float)cx; sc[1] = (float)cy;
                sc[2] = (float)(v[3] * inv - cx * cy);
                sc[3] = (float)(v[4] * inv - cx * cx);
                sc[4] = (float)(v[5] * inv - cy * cy);
            }
        }
        __syncthreads();
    }
}

// ================= fallback path (R6 kernels, used only if coop launch fails) =================
#define TX 64
#define TY 16
#define SU_STRIDE 72
#define SH_STRIDE 64
#define BLK_PER_BATCH 256
#define PART_ITER_STRIDE (BB*BLK_PER_BATCH*8)

__device__ __forceinline__ void reduce6_store(float v[6], float* dst8) {
    #pragma unroll
    for (int kk = 0; kk < 6; kk++) {
        float x = v[kk];
        #pragma unroll
        for (int off = 32; off > 0; off >>= 1) x += __shfl_down(x, off, 64);
        v[kk] = x;
    }
    __shared__ float sm[4][6];
    const int lane = threadIdx.x & 63;
    const int wv   = threadIdx.x >> 6;
    if (lane == 0) {
        #pragma unroll
        for (int kk = 0; kk < 6; kk++) sm[wv][kk] = v[kk];
    }
    __syncthreads();
    if (threadIdx.x == 0) {
        float tt[6];
        #pragma unroll
        for (int kk = 0; kk < 6; kk++) tt[kk] = sm[0][kk] + sm[1][kk] + sm[2][kk] + sm[3][kk];
        *(float4*)dst8       = make_float4(tt[0], tt[1], tt[2], tt[3]);
        *(float4*)(dst8 + 4) = make_float4(tt[4], tt[5], 0.f, 0.f);
    }
}

__global__ __launch_bounds__(256) void init_kernel(const float* __restrict__ o,
                                                   float* __restrict__ u,
                                                   float* __restrict__ q,
                                                   float* __restrict__ part0) {
    const int b     = blockIdx.x & 7;
    const int chunk = blockIdx.x >> 3;
    const int within = chunk * 1024 + threadIdx.x * 4;
    const int pix = b * NPIX + within;
    const int i = within >> 9;
    const int j = within & (WW - 1);
    float4 ov = *(const float4*)(o + pix);
    float4 uv = make_float4(sigmoidf(ov.x), sigmoidf(ov.y), sigmoidf(ov.z), sigmoidf(ov.w));
    *(float4*)(u + pix) = uv;
    *(float4*)(q + pix) = make_float4(0.f, 0.f, 0.f, 0.f);
    const float x = (float)(i + 1);
    float v[6] = {0.f, 0.f, 0.f, 0.f, 0.f, 0.f};
    float us[4] = {uv.x, uv.y, uv.z, uv.w};
    #pragma unroll
    for (int kk = 0; kk < 4; kk++) {
        float uu = us[kk];
        float y  = (float)(j + 1 + kk);
        v[0] += uu; v[1] += uu * x; v[2] += uu * y;
        v[3] += uu * x * y; v[4] += uu * x * x; v[5] += uu * y * y;
    }
    reduce6_store(v, part0 + ((size_t)b * BLK_PER_BATCH + chunk) * 8);
}

__global__ __launch_bounds__(256) void step_kernel(const float* __restrict__ o,
                                                   const float* __restrict__ uA,
                                                   const float* __restrict__ qA,
                                                   float* __restrict__ uB,
                                                   float* __restrict__ qB,
                                                   const float* __restrict__ partIn,
                                                   float* __restrict__ partOut,
                                                   float* __restrict__ out,
                                                   int lastFlag) {
    const int b    = blockIdx.x & 7;
    const int tile = blockIdx.x >> 3;
    const int j0 = (tile & 7) * TX;
    const int i0 = (tile >> 3) * TY;
    const float* ubase = uA + (size_t)b * NPIX;
    const float* qbase = qA + (size_t)b * NPIX;

    __shared__ __align__(16) float su[TY + 4][SU_STRIDE];
    __shared__ __align__(16) float sh[TY + 4][SH_STRIDE];
    __shared__ float smF[4][6];
    __shared__ float sc2[5];

    const int lin = threadIdx.x;
    const float* Pin = partIn + (size_t)b * BLK_PER_BATCH * 8 + lin * 8;
    const float4 pa = *(const float4*)Pin;
    const float4 pb = *(const float4*)(Pin + 4);

    #pragma unroll
    for (int e = lin; e < (TY + 4) * 16; e += 256) {
        const int r = e >> 4, g = e & 15;
        const int ii = i0 + r - 2;
        float4 v = make_float4(0.f, 0.f, 0.f, 0.f);
        if (ii >= 0 && ii < HH) v = *(const float4*)(ubase + ii * WW + j0 + 4 * g);
        *(float4*)&su[r][4 * g + 4] = v;
    }
    if (lin < TY + 4) {
        const int r = lin;
        const int ii = i0 + r - 2;
        float2 lv = make_float2(0.f, 0.f);
        float2 rv = make_float2(0.f, 0.f);
        if (ii >= 0 && ii < HH) {
            if (j0 > 0)       lv = *(const float2*)(ubase + ii * WW + j0 - 2);
            if (j0 + TX < WW) rv = *(const float2*)(ubase + ii * WW + j0 + TX);
        }
        *(float2*)&su[r][2]  = lv;
        *(float2*)&su[r][68] = rv;
    }
    {
        float v[6] = {pa.x, pa.y, pa.z, pa.w, pb.x, pb.y};
        #pragma unroll
        for (int off = 32; off > 0; off >>= 1) {
            #pragma unroll
            for (int c = 0; c < 6; c++) v[c] += __shfl_down(v[c], off, 64);
        }
        if ((lin & 63) == 0) {
            #pragma unroll
            for (int c = 0; c < 6; c++) smF[lin >> 6][c] = v[c];
        }
    }
    __syncthreads();
    if (lin == 0) {
        double v[6];
        #pragma unroll
        for (int c = 0; c < 6; c++)
            v[c] = (double)smF[0][c] + (double)smF[1][c] + (double)smF[2][c] + (double)smF[3][c];
        const double s = v[0], inv = 1.0 / s;
        const double cx = v[1] * inv, cy = v[2] * inv;
        sc2[0] = (float)cx; sc2[1] = (float)cy;
        sc2[2] = (float)(v[3] * inv - cx * cy);
        sc2[3] = (float)(v[4] * inv - cx * cx);
        sc2[4] = (float)(v[5] * inv - cy * cy);
    }
    #pragma unroll
    for (int e = lin; e < (TY + 4) * 16; e += 256) {
        const int r = e >> 4, g = e & 15;
        const int cc = 4 * g;
        const float4 A  = *(const float4*)&su[r][cc];
        const float4 Bv = *(const float4*)&su[r][cc + 4];
        const float4 Cv = *(const float4*)&su[r][cc + 8];
        const float v0 = A.z,  v1 = A.w,  v2 = Bv.x, v3 = Bv.y;
        const float v4 = Bv.z, v5 = Bv.w, v6 = Cv.x, v7 = Cv.y;
        float4 hres;
        hres.x = W0f*v0 + W1f*v1 + v2 + W1f*v3 + W0f*v4;
        hres.y = W0f*v1 + W1f*v2 + v3 + W1f*v4 + W0f*v5;
        hres.z = W0f*v2 + W1f*v3 + v4 + W1f*v5 + W0f*v6;
        hres.w = W0f*v3 + W1f*v4 + v5 + W1f*v6 + W0f*v7;
        *(float4*)&sh[r][cc] = hres;
    }
    __syncthreads();

    const float cxf = sc2[0], cyf = sc2[1], cossin = sc2[2], bsin = sc2[3], asin_ = sc2[4];
    const int tx = lin & 15, ty = lin >> 4;
    const int i  = i0 + ty;
    const int jb = j0 + 4 * tx;
    const int loff = i * WW + jb;
    const size_t goff = (size_t)b * NPIX + loff;

    float p4[4];
    {
        const float4 r0 = *(const float4*)&sh[ty][4 * tx];
        const float4 r1 = *(const float4*)&sh[ty + 1][4 * tx];
        const float4 r2 = *(const float4*)&sh[ty + 2][4 * tx];
        const float4 r3 = *(const float4*)&sh[ty + 3][4 * tx];
        const float4 r4 = *(const float4*)&sh[ty + 4][4 * tx];
        const float cU0 = W0f*r0.x + W1f*r1.x + r2.x + W1f*r3.x + W0f*r4.x;
        const float cU1 = W0f*r0.y + W1f*r1.y + r2.y + W1f*r3.y + W0f*r4.y;
        const float cU2 = W0f*r0.z + W1f*r1.z + r2.z + W1f*r3.z + W0f*r4.z;
        const float cU3 = W0f*r0.w + W1f*r1.w + r2.w + W1f*r3.w + W0f*r4.w;
        const float Ri = edge1d(i);
        p4[0] = INV_NORM * (Ri * edge1d(jb)     - 2.0f * cU0);
        p4[1] = INV_NORM * (Ri * edge1d(jb + 1) - 2.0f * cU1);
        p4[2] = INV_NORM * (Ri * edge1d(jb + 2) - 2.0f * cU2);
        p4[3] = INV_NORM * (Ri * edge1d(jb + 3) - 2.0f * cU3);
    }
    const float4 u1a = *(const float4*)&su[ty + 1][4 * tx + 4];
    const float4 u1b = *(const float4*)&su[ty + 1][4 * tx + 8];
    const float4 u2z = *(const float4*)&su[ty + 2][4 * tx];
    const float4 u2a = *(const float4*)&su[ty + 2][4 * tx + 4];
    const float4 u2b = *(const float4*)&su[ty + 2][4 * tx + 8];
    const float4 u3z = *(const float4*)&su[ty + 3][4 * tx];
    const float4 u3a = *(const float4*)&su[ty + 3][4 * tx + 4];
    const float uc[5] = {u2a.x, u2a.y, u2a.z, u2a.w, u2b.x};
    const float ud[4] = {u3a.x, u3a.y, u3a.z, u3a.w};
    const float uu[5] = {u1a.x, u1a.y, u1a.z, u1a.w, u1b.x};

    const float4 qc4 = *(const float4*)(qbase + loff);
    const float4 qu4 = *(const float4*)(qbase + ((i > 0) ? loff - WW : loff));
    const float  qlv = qbase[(jb > 0) ? loff - 1 : loff];
    const float4 o4  = *(const float4*)(o + goff);

    const float dx  = (float)(i + 1) - cxf;
    const float dxu = (float)i - cxf;
    const float qcv[4] = {qc4.x, qc4.y, qc4.z, qc4.w};
    const float quv[4] = {qu4.x, qu4.y, qu4.z, qu4.w};
    const float ov4[4] = {o4.x, o4.y, o4.z, o4.w};

    float a_c[4], b_c[4], qn[4], a_u[4];
    #pragma unroll
    for (int kk = 0; kk < 4; kk++) {
        const float dy = (float)(jb + kk + 1) - cyf;
        evalF(uc[kk], ud[kk], uc[kk + 1], qcv[kk], dx, dy, cossin, bsin, asin_, a_c[kk], b_c[kk], qn[kk]);
        float au, bu_d, qu_d;
        evalF(uu[kk], uc[kk], uu[kk + 1], quv[kk], dxu, dy, cossin, bsin, asin_, au, bu_d, qu_d);
        a_u[kk] = (i > 0) ? au : 0.f;
    }
    float b_l = 0.f;
    {
        float al_d, bl, ql_d;
        evalF(u2z.w, u3z.w, uc[0], qlv, dx, (float)jb - cyf, cossin, bsin, asin_, al_d, bl, ql_d);
        b_l = (jb > 0) ? bl : 0.f;
    }
    float un4[4], t4[4];
    #pragma unroll
    for (int kk = 0; kk < 4; kk++) {
        const float bleft = (kk == 0) ? b_l : b_c[kk - 1];
        const float Tq = a_c[kk] + b_c[kk] - a_u[kk] - bleft;
        t4[kk]  = ov4[kk] - p4[kk] - Tq;
        un4[kk] = sigmoidf(t4[kk]);
    }
    *(float4*)(uB + goff) = make_float4(un4[0], un4[1], un4[2], un4[3]);
    *(float4*)(qB + goff) = make_float4(qn[0], qn[1], qn[2], qn[3]);
    if (lastFlag) *(float4*)(out + goff) = make_float4(t4[0], t4[1], t4[2], t4[3]);

    const float x = (float)(i + 1);
    float s0 = 0.f, sy = 0.f, syy = 0.f;
    #pragma unroll
    for (int kk = 0; kk < 4; kk++) {
        const float y = (float)(jb + kk + 1);
        s0 += un4[kk]; sy += un4[kk] * y; syy += un4[kk] * y * y;
    }
    float v[6] = {s0, x * s0, sy, x * sy, x * x * s0, syy};
    reduce6_store(v, partOut + ((size_t)b * BLK_PER_BATCH + tile) * 8);
}

extern "C" void kernel_launch(void* const* d_in, const int* in_sizes, int n_in,
                              void* d_out, int out_size, void* d_ws, size_t ws_size,
                              hipStream_t stream) {
    const float* o = (const float*)d_in[0];
    float* out = (float*)d_out;
    float* ws = (float*)d_ws;

    // cooperative-path buffers
    float* hU = ws;                              // 2*256*4*512 = 1,048,576 floats
    float* hQ = hU + 2 * PBLK * 4 * 512;         // 2*256*512   =   262,144 floats
    float* pp = hQ + 2 * PBLK * 512;             // 2*8*32*8    =     4,096 floats

    const float* oArg = o;
    float* outArg = out;
    float* hUa = hU; float* hQa = hQ; float* ppa = pp;
    void* args[] = {(void*)&oArg, (void*)&outArg, (void*)&hUa, (void*)&hQa, (void*)&ppa};

    (void)hipFuncSetAttribute((const void*)persist_kernel,
                              hipFuncAttributeMaxDynamicSharedMemorySize, LDS_BYTES);
    hipError_t err = hipLaunchCooperativeKernel((void*)persist_kernel,
                                                dim3(PBLK), dim3(PTHR),
                                                args, LDS_BYTES, stream);
    if (err == hipSuccess) return;

    // ---------- fallback: R6 multi-kernel path ----------
    float* uA = ws + (size_t)2 * 1024 * 1024;     // past coop buffers
    float* uB = uA + (size_t)NTOT;
    float* qA = uB + (size_t)NTOT;
    float* qB = qA + (size_t)NTOT;
    float* partials = qB + (size_t)NTOT;

    init_kernel<<<2048, 256, 0, stream>>>(o, uA, qA, partials);
    float *ua = uA, *ub = uB, *qa = qA, *qb = qB;
    for (int k = 0; k < ITER; k++) {
        step_kernel<<<2048, 256, 0, stream>>>(
            o, ua, qa, ub, qb,
            partials + (size_t)k * PART_ITER_STRIDE,
            partials + (size_t)(k + 1) * PART_ITER_STRIDE,
            out, (k == ITER - 1) ? 1 : 0);
        float* tmp;
        tmp = ua; ua = ub; ub = tmp;
        tmp = qa; qa = qb; qb = tmp;
    }
}

// Round 9
// 894.149 us; speedup vs baseline: 2.8385x; 2.8385x over previous
//
#include <hip/hip_runtime.h>
#include <math.h>

#define HH 512
#define WW 512
#define BB 8
#define NPIX (HH*WW)        // 262144
#define NTOT (BB*NPIX)      // 2097152
#define ITER 50

#define TX 64
#define TY 16
#define SU_STRIDE 72        // floats; 288B rows, 16B-aligned

#define BLK_PER_BATCH 256
#define PART_ITER_STRIDE (BB*BLK_PER_BATCH*8)   // 16384 floats per iteration

// Gaussian 5x5 (sigma=5)
constexpr double W0d = 0.92311634638663587;  // exp(-0.08)
constexpr double W1d = 0.98019867330675525;  // exp(-0.02)
constexpr double SUM1D = 1.0 + 2.0*(W0d + W1d);
constexpr float  INV_NORM = (float)(1.0/(SUM1D*SUM1D + 1e-15));
constexpr float  W0f = (float)W0d;
constexpr float  W1f = (float)W1d;
constexpr float  S1f = (float)SUM1D;

__device__ __forceinline__ float sigmoidf(float x) { return 1.0f / (1.0f + expf(-x)); }

__device__ __forceinline__ float edge1d(int v) {
    float r = S1f;
    if (v == 0 || v == HH - 1) r = S1f - W0f - W1f;
    else if (v == 1 || v == HH - 2) r = S1f - W0f;
    return r;
}

// Block-level reduce of 6 floats, one plain store to private partials slot.
__device__ __forceinline__ void reduce6_store(float v[6], float* dst8) {
    #pragma unroll
    for (int kk = 0; kk < 6; kk++) {
        float x = v[kk];
        #pragma unroll
        for (int off = 32; off > 0; off >>= 1) x += __shfl_down(x, off, 64);
        v[kk] = x;
    }
    __shared__ float sm[4][6];
    const int lane = threadIdx.x & 63;
    const int wv   = threadIdx.x >> 6;
    if (lane == 0) {
        #pragma unroll
        for (int kk = 0; kk < 6; kk++) sm[wv][kk] = v[kk];
    }
    __syncthreads();
    if (threadIdx.x == 0) {
        float tt[6];
        #pragma unroll
        for (int kk = 0; kk < 6; kk++) tt[kk] = sm[0][kk] + sm[1][kk] + sm[2][kk] + sm[3][kk];
        *(float4*)dst8       = make_float4(tt[0], tt[1], tt[2], tt[3]);
        *(float4*)(dst8 + 4) = make_float4(tt[4], tt[5], 0.f, 0.f);
    }
}

__device__ __forceinline__ void evalF(float uc, float ud, float ur, float qv,
                                      float dx, float dy,
                                      float cossin, float bsin, float asin_,
                                      float& a, float& bv, float& qn) {
    float Tx = -dx * cossin + dy * bsin;
    float Ty =  dy * cossin - dx * asin_;
    const float rn = 1.0f / (sqrtf(Tx * Tx + Ty * Ty) + 1e-10f);
    Tx *= rn; Ty *= rn;
    qn = qv - ((ud - uc) * Tx + (ur - uc) * Ty);
    a  = Tx * qn;
    bv = Ty * qn;
}

// u0 = sigmoid(o); q0 = 0; write partials[0]. XCD swizzle: batch = blk & 7.
__global__ __launch_bounds__(256) void init_kernel(const float* __restrict__ o,
                                                   float* __restrict__ u,
                                                   float* __restrict__ q,
                                                   float* __restrict__ part0) {
    const int b     = blockIdx.x & 7;
    const int chunk = blockIdx.x >> 3;
    const int within = chunk * 1024 + threadIdx.x * 4;
    const int pix = b * NPIX + within;
    const int i = within >> 9;
    const int j = within & (WW - 1);
    float4 ov = *(const float4*)(o + pix);
    float4 uv = make_float4(sigmoidf(ov.x), sigmoidf(ov.y), sigmoidf(ov.z), sigmoidf(ov.w));
    *(float4*)(u + pix) = uv;
    *(float4*)(q + pix) = make_float4(0.f, 0.f, 0.f, 0.f);
    const float x = (float)(i + 1);
    float v[6] = {0.f, 0.f, 0.f, 0.f, 0.f, 0.f};
    float us[4] = {uv.x, uv.y, uv.z, uv.w};
    #pragma unroll
    for (int kk = 0; kk < 4; kk++) {
        float uu = us[kk];
        float y  = (float)(j + 1 + kk);
        v[0] += uu; v[1] += uu * x; v[2] += uu * y;
        v[3] += uu * x * y; v[4] += uu * x * x; v[5] += uu * y * y;
    }
    reduce6_store(v, part0 + ((size_t)b * BLK_PER_BATCH + chunk) * 8);
}

// One fused iteration. Entry-prefetched loads, 2 barriers total, no sh array,
// per-wave redundant scalar finalize (no LDS, no barrier for scalars).
// su col t <-> img col j0 + t - 4 (t=2..69 valid); su row r <-> img row i0 + r - 2.
__global__ __launch_bounds__(256) void step_kernel(const float* __restrict__ o,
                                                   const float* __restrict__ uA,
                                                   const float* __restrict__ qA,
                                                   float* __restrict__ uB,
                                                   float* __restrict__ qB,
                                                   const float* __restrict__ partIn,
                                                   float* __restrict__ partOut,
                                                   float* __restrict__ out,
                                                   int lastFlag) {
    const int b    = blockIdx.x & 7;
    const int tile = blockIdx.x >> 3;
    const int j0 = (tile & 7) * TX;
    const int i0 = (tile >> 3) * TY;
    const float* ubase = uA + (size_t)b * NPIX;
    const float* qbase = qA + (size_t)b * NPIX;

    __shared__ __align__(16) float su[TY + 4][SU_STRIDE];

    const int lin  = threadIdx.x;
    const int lane = lin & 63;
    const int tx = lin & 15;
    const int ty = lin >> 4;
    const int i  = i0 + ty;
    const int jb = j0 + 4 * tx;
    const int loff = i * WW + jb;
    const size_t goff = (size_t)b * NPIX + loff;

    // ======== entry: issue ALL global loads ========
    // partials: each wave covers all 256 slots of this batch (lane + 64s)
    float4 pA[4], pB[4];
    #pragma unroll
    for (int s = 0; s < 4; s++) {
        const float* P = partIn + (size_t)b * (BLK_PER_BATCH * 8) + (lane + 64 * s) * 8;
        pA[s] = *(const float4*)P;
        pB[s] = *(const float4*)(P + 4);
    }
    // staging: 20 rows x 16 groups = 320 float4 tasks; threads lin<64 take 2
    const int e0 = lin;
    const int r0 = e0 >> 4, g0 = e0 & 15;
    const int ii0 = i0 + r0 - 2;
    float4 sv0 = make_float4(0.f, 0.f, 0.f, 0.f);
    if (ii0 >= 0 && ii0 < HH) sv0 = *(const float4*)(ubase + ii0 * WW + j0 + 4 * g0);
    const int e1 = lin + 256;
    const int r1 = e1 >> 4, g1 = e1 & 15;
    float4 sv1 = make_float4(0.f, 0.f, 0.f, 0.f);
    if (lin < 64) {
        const int ii1 = i0 + r1 - 2;
        if (ii1 >= 0 && ii1 < HH) sv1 = *(const float4*)(ubase + ii1 * WW + j0 + 4 * g1);
    }
    // halo columns
    float2 lv = make_float2(0.f, 0.f);
    float2 rv = make_float2(0.f, 0.f);
    if (lin < TY + 4) {
        const int iih = i0 + lin - 2;
        if (iih >= 0 && iih < HH) {
            if (j0 > 0)       lv = *(const float2*)(ubase + iih * WW + j0 - 2);
            if (j0 + TX < WW) rv = *(const float2*)(ubase + iih * WW + j0 + TX);
        }
    }
    // q / o (clamped addresses)
    const float4 qc4 = *(const float4*)(qbase + loff);
    const float4 qu4 = *(const float4*)(qbase + ((i > 0) ? loff - WW : loff));
    const float  qlv = qbase[(jb > 0) ? loff - 1 : loff];
    const float4 o4  = *(const float4*)(o + goff);

    // ======== per-wave scalar finalize (butterfly, no LDS / no barrier) ========
    float v6[6] = {0.f, 0.f, 0.f, 0.f, 0.f, 0.f};
    #pragma unroll
    for (int s = 0; s < 4; s++) {
        v6[0] += pA[s].x; v6[1] += pA[s].y; v6[2] += pA[s].z;
        v6[3] += pA[s].w; v6[4] += pB[s].x; v6[5] += pB[s].y;
    }
    #pragma unroll
    for (int mask = 1; mask < 64; mask <<= 1) {
        #pragma unroll
        for (int c = 0; c < 6; c++) v6[c] += __shfl_xor(v6[c], mask, 64);
    }
    const double sS  = (double)v6[0];
    const double inv = 1.0 / sS;
    const double cxd = (double)v6[1] * inv;
    const double cyd = (double)v6[2] * inv;
    const float cxf    = (float)cxd;
    const float cyf    = (float)cyd;
    const float cossin = (float)((double)v6[3] * inv - cxd * cyd);
    const float bsin   = (float)((double)v6[4] * inv - cxd * cxd);
    const float asin_  = (float)((double)v6[5] * inv - cyd * cyd);

    // ======== stage to LDS, single barrier ========
    *(float4*)&su[r0][4 * g0 + 4] = sv0;
    if (lin < 64) *(float4*)&su[r1][4 * g1 + 4] = sv1;
    if (lin < TY + 4) {
        *(float2*)&su[lin][2]  = lv;
        *(float2*)&su[lin][68] = rv;
    }
    __syncthreads();

    // ======== per-thread conv (v-pass first) + eval rows from su ========
    float vs[8];
    float Ru[8], Rc[8], Rd[8];   // rows i-1, i, i+1 (su cols 4tx+2..4tx+9)
    {
        // row ty (i-2)
        float4 A = *(const float4*)&su[ty][4 * tx];
        float4 Bv = *(const float4*)&su[ty][4 * tx + 4];
        float4 C = *(const float4*)&su[ty][4 * tx + 8];
        vs[0] = W0f * A.z;  vs[1] = W0f * A.w;
        vs[2] = W0f * Bv.x; vs[3] = W0f * Bv.y; vs[4] = W0f * Bv.z; vs[5] = W0f * Bv.w;
        vs[6] = W0f * C.x;  vs[7] = W0f * C.y;
        // row ty+1 (i-1)
        A = *(const float4*)&su[ty + 1][4 * tx];
        Bv = *(const float4*)&su[ty + 1][4 * tx + 4];
        C = *(const float4*)&su[ty + 1][4 * tx + 8];
        Ru[0] = A.z; Ru[1] = A.w; Ru[2] = Bv.x; Ru[3] = Bv.y;
        Ru[4] = Bv.z; Ru[5] = Bv.w; Ru[6] = C.x; Ru[7] = C.y;
        #pragma unroll
        for (int c = 0; c < 8; c++) vs[c] += W1f * Ru[c];
        // row ty+2 (i)
        A = *(const float4*)&su[ty + 2][4 * tx];
        Bv = *(const float4*)&su[ty + 2][4 * tx + 4];
        C = *(const float4*)&su[ty + 2][4 * tx + 8];
        Rc[0] = A.z; Rc[1] = A.w; Rc[2] = Bv.x; Rc[3] = Bv.y;
        Rc[4] = Bv.z; Rc[5] = Bv.w; Rc[6] = C.x; Rc[7] = C.y;
        #pragma unroll
        for (int c = 0; c < 8; c++) vs[c] += Rc[c];
        // row ty+3 (i+1)
        A = *(const float4*)&su[ty + 3][4 * tx];
        Bv = *(const float4*)&su[ty + 3][4 * tx + 4];
        C = *(const float4*)&su[ty + 3][4 * tx + 8];
        Rd[0] = A.z; Rd[1] = A.w; Rd[2] = Bv.x; Rd[3] = Bv.y;
        Rd[4] = Bv.z; Rd[5] = Bv.w; Rd[6] = C.x; Rd[7] = C.y;
        #pragma unroll
        for (int c = 0; c < 8; c++) vs[c] += W1f * Rd[c];
        // row ty+4 (i+2)
        A = *(const float4*)&su[ty + 4][4 * tx];
        Bv = *(const float4*)&su[ty + 4][4 * tx + 4];
        C = *(const float4*)&su[ty + 4][4 * tx + 8];
        vs[0] += W0f * A.z;  vs[1] += W0f * A.w;
        vs[2] += W0f * Bv.x; vs[3] += W0f * Bv.y; vs[4] += W0f * Bv.z; vs[5] += W0f * Bv.w;
        vs[6] += W0f * C.x;  vs[7] += W0f * C.y;
    }
    const float Ri = edge1d(i);
    float p4[4];
    #pragma unroll
    for (int k = 0; k < 4; k++) {
        const float convU = W0f * vs[k] + W1f * vs[k + 1] + vs[k + 2]
                          + W1f * vs[k + 3] + W0f * vs[k + 4];
        p4[k] = INV_NORM * (Ri * edge1d(jb + k) - 2.0f * convU);
    }

    const float dx  = (float)(i + 1) - cxf;
    const float dxu = (float)i - cxf;
    const float qcv[4] = {qc4.x, qc4.y, qc4.z, qc4.w};
    const float quv[4] = {qu4.x, qu4.y, qu4.z, qu4.w};
    const float ov4[4] = {o4.x, o4.y, o4.z, o4.w};

    float a_c[4], b_c[4], qn[4], a_u[4];
    #pragma unroll
    for (int k = 0; k < 4; k++) {
        const float dy = (float)(jb + k + 1) - cyf;
        // center eval: uc=u(i,j), ud=u(i+1,j), ur=u(i,j+1)  [Rc idx k+2 is col jb+k]
        evalF(Rc[k + 2], Rd[k + 2], Rc[k + 3], qcv[k],
              dx, dy, cossin, bsin, asin_, a_c[k], b_c[k], qn[k]);
        float au, bu_d, qu_d;
        evalF(Ru[k + 2], Rc[k + 2], Ru[k + 3], quv[k],
              dxu, dy, cossin, bsin, asin_, au, bu_d, qu_d);
        a_u[k] = (i > 0) ? au : 0.f;
    }
    float b_l = 0.f;
    {
        float al_d, bl, ql_d;
        evalF(Rc[1], Rd[1], Rc[2], qlv,
              dx, (float)jb - cyf, cossin, bsin, asin_, al_d, bl, ql_d);
        b_l = (jb > 0) ? bl : 0.f;
    }

    float un4[4], t4[4];
    #pragma unroll
    for (int k = 0; k < 4; k++) {
        const float bleft = (k == 0) ? b_l : b_c[k - 1];
        const float Tq = a_c[k] + b_c[k] - a_u[k] - bleft;
        t4[k]  = ov4[k] - p4[k] - Tq;
        un4[k] = sigmoidf(t4[k]);
    }

    *(float4*)(uB + goff) = make_float4(un4[0], un4[1], un4[2], un4[3]);
    *(float4*)(qB + goff) = make_float4(qn[0], qn[1], qn[2], qn[3]);
    if (lastFlag) *(float4*)(out + goff) = make_float4(t4[0], t4[1], t4[2], t4[3]);

    // next-iteration partial sums (atomic-free)
    const float x = (float)(i + 1);
    float s0 = 0.f, sy = 0.f, syy = 0.f;
    #pragma unroll
    for (int k = 0; k < 4; k++) {
        const float y = (float)(jb + k + 1);
        s0 += un4[k]; sy += un4[k] * y; syy += un4[k] * y * y;
    }
    float v[6] = {s0, x * s0, sy, x * sy, x * x * s0, syy};
    reduce6_store(v, partOut + ((size_t)b * BLK_PER_BATCH + tile) * 8);
}

extern "C" void kernel_launch(void* const* d_in, const int* in_sizes, int n_in,
                              void* d_out, int out_size, void* d_ws, size_t ws_size,
                              hipStream_t stream) {
    const float* o = (const float*)d_in[0];
    float* out = (float*)d_out;

    float* ws = (float*)d_ws;
    float* uA = ws;
    float* uB = ws + (size_t)NTOT;
    float* qA = ws + 2 * (size_t)NTOT;
    float* qB = ws + 3 * (size_t)NTOT;
    float* partials = ws + 4 * (size_t)NTOT;   // 51 iters * 16384 floats

    init_kernel<<<2048, 256, 0, stream>>>(o, uA, qA, partials);

    float *ua = uA, *ub = uB, *qa = qA, *qb = qB;
    for (int k = 0; k < ITER; k++) {
        step_kernel<<<2048, 256, 0, stream>>>(
            o, ua, qa, ub, qb,
            partials + (size_t)k * PART_ITER_STRIDE,
            partials + (size_t)(k + 1) * PART_ITER_STRIDE,
            out, (k == ITER - 1) ? 1 : 0);
        float* tmp;
        tmp = ua; ua = ub; ub = tmp;
        tmp = qa; qa = qb; qb = tmp;
    }
}

// Round 10
// 876.839 us; speedup vs baseline: 2.8945x; 1.0197x over previous
//
#include <hip/hip_runtime.h>
#include <math.h>

typedef _Float16 h16;
typedef h16 half8  __attribute__((ext_vector_type(8)));
typedef h16 half4v __attribute__((ext_vector_type(4)));
typedef h16 half2v __attribute__((ext_vector_type(2)));

#define HH 512
#define WW 512
#define BB 8
#define NPIX (HH*WW)        // 262144
#define NTOT (BB*NPIX)      // 2097152
#define ITER 50

#define TX 64
#define TY 16
#define SU_STRIDE 72        // floats; 288B rows, 16B-aligned

#define BLK_PER_BATCH 256
#define PART_ITER_STRIDE (BB*BLK_PER_BATCH*8)   // 16384 floats per iteration

// Gaussian 5x5 (sigma=5)
constexpr double W0d = 0.92311634638663587;  // exp(-0.08)
constexpr double W1d = 0.98019867330675525;  // exp(-0.02)
constexpr double SUM1D = 1.0 + 2.0*(W0d + W1d);
constexpr float  INV_NORM = (float)(1.0/(SUM1D*SUM1D + 1e-15));
constexpr float  W0f = (float)W0d;
constexpr float  W1f = (float)W1d;
constexpr float  S1f = (float)SUM1D;

__device__ __forceinline__ float sigmoidf(float x) { return 1.0f / (1.0f + expf(-x)); }

__device__ __forceinline__ float edge1d(int v) {
    float r = S1f;
    if (v == 0 || v == HH - 1) r = S1f - W0f - W1f;
    else if (v == 1 || v == HH - 2) r = S1f - W0f;
    return r;
}

// Block-level reduce of 6 floats, one plain store to private partials slot.
__device__ __forceinline__ void reduce6_store(float v[6], float* dst8) {
    #pragma unroll
    for (int kk = 0; kk < 6; kk++) {
        float x = v[kk];
        #pragma unroll
        for (int off = 32; off > 0; off >>= 1) x += __shfl_down(x, off, 64);
        v[kk] = x;
    }
    __shared__ float sm[4][6];
    const int lane = threadIdx.x & 63;
    const int wv   = threadIdx.x >> 6;
    if (lane == 0) {
        #pragma unroll
        for (int kk = 0; kk < 6; kk++) sm[wv][kk] = v[kk];
    }
    __syncthreads();
    if (threadIdx.x == 0) {
        float tt[6];
        #pragma unroll
        for (int kk = 0; kk < 6; kk++) tt[kk] = sm[0][kk] + sm[1][kk] + sm[2][kk] + sm[3][kk];
        *(float4*)dst8       = make_float4(tt[0], tt[1], tt[2], tt[3]);
        *(float4*)(dst8 + 4) = make_float4(tt[4], tt[5], 0.f, 0.f);
    }
}

__device__ __forceinline__ void evalF(float uc, float ud, float ur, float qv,
                                      float dx, float dy,
                                      float cossin, float bsin, float asin_,
                                      float& a, float& bv, float& qn) {
    float Tx = -dx * cossin + dy * bsin;
    float Ty =  dy * cossin - dx * asin_;
    const float rn = 1.0f / (sqrtf(Tx * Tx + Ty * Ty) + 1e-10f);
    Tx *= rn; Ty *= rn;
    qn = qv - ((ud - uc) * Tx + (ur - uc) * Ty);
    a  = Tx * qn;
    bv = Ty * qn;
}

// u0 = sigmoid(o) (rounded to fp16); q0 = 0; o -> fp16; partials[0] from rounded u.
__global__ __launch_bounds__(256) void init_kernel(const float* __restrict__ o,
                                                   h16* __restrict__ u,
                                                   h16* __restrict__ q,
                                                   h16* __restrict__ oh,
                                                   float* __restrict__ part0) {
    const int b     = blockIdx.x & 7;
    const int chunk = blockIdx.x >> 3;
    const int within = chunk * 1024 + threadIdx.x * 4;
    const int pix = b * NPIX + within;
    const int i = within >> 9;
    const int j = within & (WW - 1);
    float4 ov = *(const float4*)(o + pix);

    half4v oh4; half4v uh4; half4v qz;
    float urf[4];
    const float uv[4] = {sigmoidf(ov.x), sigmoidf(ov.y), sigmoidf(ov.z), sigmoidf(ov.w)};
    const float of[4] = {ov.x, ov.y, ov.z, ov.w};
    #pragma unroll
    for (int kk = 0; kk < 4; kk++) {
        oh4[kk] = (h16)of[kk];
        uh4[kk] = (h16)uv[kk];
        urf[kk] = (float)uh4[kk];
        qz[kk]  = (h16)0.f;
    }
    *(half4v*)(u + pix)  = uh4;
    *(half4v*)(q + pix)  = qz;
    *(half4v*)(oh + pix) = oh4;

    const float x = (float)(i + 1);
    float v[6] = {0.f, 0.f, 0.f, 0.f, 0.f, 0.f};
    #pragma unroll
    for (int kk = 0; kk < 4; kk++) {
        const float uu = urf[kk];
        const float y  = (float)(j + 1 + kk);
        v[0] += uu; v[1] += uu * x; v[2] += uu * y;
        v[3] += uu * x * y; v[4] += uu * x * x; v[5] += uu * y * y;
    }
    reduce6_store(v, part0 + ((size_t)b * BLK_PER_BATCH + chunk) * 8);
}

// One fused iteration, fp16 state. Entry-prefetched loads, 2 barriers,
// per-wave butterfly scalar finalize, v-pass-first conv from LDS(fp32).
__global__ __launch_bounds__(256) void step_kernel(const h16* __restrict__ oh,
                                                   const h16* __restrict__ uA,
                                                   const h16* __restrict__ qA,
                                                   h16* __restrict__ uB,
                                                   h16* __restrict__ qB,
                                                   const float* __restrict__ partIn,
                                                   float* __restrict__ partOut,
                                                   float* __restrict__ out,
                                                   int lastFlag) {
    const int b    = blockIdx.x & 7;
    const int tile = blockIdx.x >> 3;
    const int j0 = (tile & 7) * TX;
    const int i0 = (tile >> 3) * TY;
    const h16* ubase = uA + (size_t)b * NPIX;
    const h16* qbase = qA + (size_t)b * NPIX;

    __shared__ __align__(16) float su[TY + 4][SU_STRIDE];

    const int lin  = threadIdx.x;
    const int lane = lin & 63;
    const int tx = lin & 15;
    const int ty = lin >> 4;
    const int i  = i0 + ty;
    const int jb = j0 + 4 * tx;
    const int loff = i * WW + jb;
    const size_t goff = (size_t)b * NPIX + loff;

    // ======== entry: issue ALL global loads ========
    float4 pA[4], pB[4];
    #pragma unroll
    for (int s = 0; s < 4; s++) {
        const float* P = partIn + (size_t)b * (BLK_PER_BATCH * 8) + (lane + 64 * s) * 8;
        pA[s] = *(const float4*)P;
        pB[s] = *(const float4*)(P + 4);
    }
    // staging: 20 rows x 8 groups (8 cols, 16B) = 160 tasks, 1 per thread (lin<160)
    half8 sv; 
    #pragma unroll
    for (int c = 0; c < 8; c++) sv[c] = (h16)0.f;
    const int r0 = lin >> 3, g0 = lin & 7;
    if (lin < 160) {
        const int ii0 = i0 + r0 - 2;
        if (ii0 >= 0 && ii0 < HH) sv = *(const half8*)(ubase + ii0 * WW + j0 + 8 * g0);
    }
    // halo columns (2 each side)
    half2v lv, rv;
    lv[0] = (h16)0.f; lv[1] = (h16)0.f; rv[0] = (h16)0.f; rv[1] = (h16)0.f;
    if (lin < TY + 4) {
        const int iih = i0 + lin - 2;
        if (iih >= 0 && iih < HH) {
            if (j0 > 0)       lv = *(const half2v*)(ubase + iih * WW + j0 - 2);
            if (j0 + TX < WW) rv = *(const half2v*)(ubase + iih * WW + j0 + TX);
        }
    }
    // q / o (clamped addresses)
    const half4v qc4h = *(const half4v*)(qbase + loff);
    const half4v qu4h = *(const half4v*)(qbase + ((i > 0) ? loff - WW : loff));
    const h16    qlh  = qbase[(jb > 0) ? loff - 1 : loff];
    const half4v o4h  = *(const half4v*)(oh + goff);

    // ======== per-wave scalar finalize (butterfly) ========
    float v6[6] = {0.f, 0.f, 0.f, 0.f, 0.f, 0.f};
    #pragma unroll
    for (int s = 0; s < 4; s++) {
        v6[0] += pA[s].x; v6[1] += pA[s].y; v6[2] += pA[s].z;
        v6[3] += pA[s].w; v6[4] += pB[s].x; v6[5] += pB[s].y;
    }
    #pragma unroll
    for (int mask = 1; mask < 64; mask <<= 1) {
        #pragma unroll
        for (int c = 0; c < 6; c++) v6[c] += __shfl_xor(v6[c], mask, 64);
    }
    const double sS  = (double)v6[0];
    const double inv = 1.0 / sS;
    const double cxd = (double)v6[1] * inv;
    const double cyd = (double)v6[2] * inv;
    const float cxf    = (float)cxd;
    const float cyf    = (float)cyd;
    const float cossin = (float)((double)v6[3] * inv - cxd * cyd);
    const float bsin   = (float)((double)v6[4] * inv - cxd * cxd);
    const float asin_  = (float)((double)v6[5] * inv - cyd * cyd);

    // ======== stage to LDS (fp32), single barrier ========
    if (lin < 160) {
        float4 f0, f1;
        f0.x = (float)sv[0]; f0.y = (float)sv[1]; f0.z = (float)sv[2]; f0.w = (float)sv[3];
        f1.x = (float)sv[4]; f1.y = (float)sv[5]; f1.z = (float)sv[6]; f1.w = (float)sv[7];
        *(float4*)&su[r0][8 * g0 + 4] = f0;
        *(float4*)&su[r0][8 * g0 + 8] = f1;
    }
    if (lin < TY + 4) {
        su[lin][2] = (float)lv[0]; su[lin][3] = (float)lv[1];
        su[lin][68] = (float)rv[0]; su[lin][69] = (float)rv[1];
    }
    __syncthreads();

    // ======== per-thread conv (v-pass first) + eval rows from su ========
    float vs[8];
    float Ru[8], Rc[8], Rd[8];   // rows i-1, i, i+1 (su cols 4tx+2..4tx+9)
    {
        float4 A = *(const float4*)&su[ty][4 * tx];
        float4 Bv = *(const float4*)&su[ty][4 * tx + 4];
        float4 C = *(const float4*)&su[ty][4 * tx + 8];
        vs[0] = W0f * A.z;  vs[1] = W0f * A.w;
        vs[2] = W0f * Bv.x; vs[3] = W0f * Bv.y; vs[4] = W0f * Bv.z; vs[5] = W0f * Bv.w;
        vs[6] = W0f * C.x;  vs[7] = W0f * C.y;
        A = *(const float4*)&su[ty + 1][4 * tx];
        Bv = *(const float4*)&su[ty + 1][4 * tx + 4];
        C = *(const float4*)&su[ty + 1][4 * tx + 8];
        Ru[0] = A.z; Ru[1] = A.w; Ru[2] = Bv.x; Ru[3] = Bv.y;
        Ru[4] = Bv.z; Ru[5] = Bv.w; Ru[6] = C.x; Ru[7] = C.y;
        #pragma unroll
        for (int c = 0; c < 8; c++) vs[c] += W1f * Ru[c];
        A = *(const float4*)&su[ty + 2][4 * tx];
        Bv = *(const float4*)&su[ty + 2][4 * tx + 4];
        C = *(const float4*)&su[ty + 2][4 * tx + 8];
        Rc[0] = A.z; Rc[1] = A.w; Rc[2] = Bv.x; Rc[3] = Bv.y;
        Rc[4] = Bv.z; Rc[5] = Bv.w; Rc[6] = C.x; Rc[7] = C.y;
        #pragma unroll
        for (int c = 0; c < 8; c++) vs[c] += Rc[c];
        A = *(const float4*)&su[ty + 3][4 * tx];
        Bv = *(const float4*)&su[ty + 3][4 * tx + 4];
        C = *(const float4*)&su[ty + 3][4 * tx + 8];
        Rd[0] = A.z; Rd[1] = A.w; Rd[2] = Bv.x; Rd[3] = Bv.y;
        Rd[4] = Bv.z; Rd[5] = Bv.w; Rd[6] = C.x; Rd[7] = C.y;
        #pragma unroll
        for (int c = 0; c < 8; c++) vs[c] += W1f * Rd[c];
        A = *(const float4*)&su[ty + 4][4 * tx];
        Bv = *(const float4*)&su[ty + 4][4 * tx + 4];
        C = *(const float4*)&su[ty + 4][4 * tx + 8];
        vs[0] += W0f * A.z;  vs[1] += W0f * A.w;
        vs[2] += W0f * Bv.x; vs[3] += W0f * Bv.y; vs[4] += W0f * Bv.z; vs[5] += W0f * Bv.w;
        vs[6] += W0f * C.x;  vs[7] += W0f * C.y;
    }
    const float Ri = edge1d(i);
    float p4[4];
    #pragma unroll
    for (int k = 0; k < 4; k++) {
        const float convU = W0f * vs[k] + W1f * vs[k + 1] + vs[k + 2]
                          + W1f * vs[k + 3] + W0f * vs[k + 4];
        p4[k] = INV_NORM * (Ri * edge1d(jb + k) - 2.0f * convU);
    }

    const float dx  = (float)(i + 1) - cxf;
    const float dxu = (float)i - cxf;
    const float qcv[4] = {(float)qc4h[0], (float)qc4h[1], (float)qc4h[2], (float)qc4h[3]};
    const float quv[4] = {(float)qu4h[0], (float)qu4h[1], (float)qu4h[2], (float)qu4h[3]};
    const float ov4[4] = {(float)o4h[0], (float)o4h[1], (float)o4h[2], (float)o4h[3]};
    const float qlv = (float)qlh;

    float a_c[4], b_c[4], qn[4], a_u[4];
    #pragma unroll
    for (int k = 0; k < 4; k++) {
        const float dy = (float)(jb + k + 1) - cyf;
        evalF(Rc[k + 2], Rd[k + 2], Rc[k + 3], qcv[k],
              dx, dy, cossin, bsin, asin_, a_c[k], b_c[k], qn[k]);
        float au, bu_d, qu_d;
        evalF(Ru[k + 2], Rc[k + 2], Ru[k + 3], quv[k],
              dxu, dy, cossin, bsin, asin_, au, bu_d, qu_d);
        a_u[k] = (i > 0) ? au : 0.f;
    }
    float b_l = 0.f;
    {
        float al_d, bl, ql_d;
        evalF(Rc[1], Rd[1], Rc[2], qlv,
              dx, (float)jb - cyf, cossin, bsin, asin_, al_d, bl, ql_d);
        b_l = (jb > 0) ? bl : 0.f;
    }

    float un4[4], t4[4];
    #pragma unroll
    for (int k = 0; k < 4; k++) {
        const float bleft = (k == 0) ? b_l : b_c[k - 1];
        const float Tq = a_c[k] + b_c[k] - a_u[k] - bleft;
        t4[k]  = ov4[k] - p4[k] - Tq;
        un4[k] = sigmoidf(t4[k]);
    }

    // round state to fp16; sums use the ROUNDED u for centroid/field consistency
    half4v uh4, qh4;
    float urf[4];
    #pragma unroll
    for (int k = 0; k < 4; k++) {
        uh4[k] = (h16)un4[k];
        urf[k] = (float)uh4[k];
        qh4[k] = (h16)qn[k];
    }
    *(half4v*)(uB + goff) = uh4;
    *(half4v*)(qB + goff) = qh4;
    if (lastFlag) *(float4*)(out + goff) = make_float4(t4[0], t4[1], t4[2], t4[3]);

    const float x = (float)(i + 1);
    float s0 = 0.f, sy = 0.f, syy = 0.f;
    #pragma unroll
    for (int k = 0; k < 4; k++) {
        const float y = (float)(jb + k + 1);
        s0 += urf[k]; sy += urf[k] * y; syy += urf[k] * y * y;
    }
    float v[6] = {s0, x * s0, sy, x * sy, x * x * s0, syy};
    reduce6_store(v, partOut + ((size_t)b * BLK_PER_BATCH + tile) * 8);
}

extern "C" void kernel_launch(void* const* d_in, const int* in_sizes, int n_in,
                              void* d_out, int out_size, void* d_ws, size_t ws_size,
                              hipStream_t stream) {
    const float* o = (const float*)d_in[0];
    float* out = (float*)d_out;

    h16* uA = (h16*)d_ws;
    h16* uB = uA + (size_t)NTOT;
    h16* qA = uB + (size_t)NTOT;
    h16* qB = qA + (size_t)NTOT;
    h16* oh = qB + (size_t)NTOT;
    float* partials = (float*)(oh + (size_t)NTOT);   // 51 iters * 16384 floats

    init_kernel<<<2048, 256, 0, stream>>>(o, uA, qA, oh, partials);

    h16 *ua = uA, *ub = uB, *qa = qA, *qb = qB;
    for (int k = 0; k < ITER; k++) {
        step_kernel<<<2048, 256, 0, stream>>>(
            oh, ua, qa, ub, qb,
            partials + (size_t)k * PART_ITER_STRIDE,
            partials + (size_t)(k + 1) * PART_ITER_STRIDE,
            out, (k == ITER - 1) ? 1 : 0);
        h16* tmp;
        tmp = ua; ua = ub; ub = tmp;
        tmp = qa; qa = qb; qb = tmp;
    }
}

// Round 11
// 868.154 us; speedup vs baseline: 2.9235x; 1.0100x over previous
//
#include <hip/hip_runtime.h>
#include <math.h>

typedef _Float16 h16;
typedef h16 half4v __attribute__((ext_vector_type(4)));
typedef h16 half2v __attribute__((ext_vector_type(2)));

#define HH 512
#define WW 512
#define BB 8
#define NPIX (HH*WW)        // 262144
#define NTOT (BB*NPIX)      // 2097152
#define ITER 50

#define TX 64
#define TY 16

#define BLK_PER_BATCH 256
#define PART_ITER_STRIDE (BB*BLK_PER_BATCH*8)   // 16384 floats per iteration

// Gaussian 5x5 (sigma=5)
constexpr double W0d = 0.92311634638663587;  // exp(-0.08)
constexpr double W1d = 0.98019867330675525;  // exp(-0.02)
constexpr double SUM1D = 1.0 + 2.0*(W0d + W1d);
constexpr float  INV_NORM = (float)(1.0/(SUM1D*SUM1D + 1e-15));
constexpr float  W0f = (float)W0d;
constexpr float  W1f = (float)W1d;
constexpr float  S1f = (float)SUM1D;

__device__ __forceinline__ float sigmoidf(float x) { return 1.0f / (1.0f + expf(-x)); }

__device__ __forceinline__ float edge1d(int v) {
    float r = S1f;
    if (v == 0 || v == HH - 1) r = S1f - W0f - W1f;
    else if (v == 1 || v == HH - 2) r = S1f - W0f;
    return r;
}

// Block-level reduce of 6 floats, one plain store to private partials slot.
__device__ __forceinline__ void reduce6_store(float v[6], float* dst8) {
    #pragma unroll
    for (int kk = 0; kk < 6; kk++) {
        float x = v[kk];
        #pragma unroll
        for (int off = 32; off > 0; off >>= 1) x += __shfl_down(x, off, 64);
        v[kk] = x;
    }
    __shared__ float sm[4][6];
    const int lane = threadIdx.x & 63;
    const int wv   = threadIdx.x >> 6;
    if (lane == 0) {
        #pragma unroll
        for (int kk = 0; kk < 6; kk++) sm[wv][kk] = v[kk];
    }
    __syncthreads();
    if (threadIdx.x == 0) {
        float tt[6];
        #pragma unroll
        for (int kk = 0; kk < 6; kk++) tt[kk] = sm[0][kk] + sm[1][kk] + sm[2][kk] + sm[3][kk];
        *(float4*)dst8       = make_float4(tt[0], tt[1], tt[2], tt[3]);
        *(float4*)(dst8 + 4) = make_float4(tt[4], tt[5], 0.f, 0.f);
    }
}

__device__ __forceinline__ void evalF(float uc, float ud, float ur, float qv,
                                      float dx, float dy,
                                      float cossin, float bsin, float asin_,
                                      float& a, float& bv, float& qn) {
    float Tx = -dx * cossin + dy * bsin;
    float Ty =  dy * cossin - dx * asin_;
    const float rn = 1.0f / (sqrtf(Tx * Tx + Ty * Ty) + 1e-10f);
    Tx *= rn; Ty *= rn;
    qn = qv - ((ud - uc) * Tx + (ur - uc) * Ty);
    a  = Tx * qn;
    bv = Ty * qn;
}

// u0 = sigmoid(o) (rounded to fp16); q0 = 0; o -> fp16; partials[0] from rounded u.
__global__ __launch_bounds__(256) void init_kernel(const float* __restrict__ o,
                                                   h16* __restrict__ u,
                                                   h16* __restrict__ q,
                                                   h16* __restrict__ oh,
                                                   float* __restrict__ part0) {
    const int b     = blockIdx.x & 7;
    const int chunk = blockIdx.x >> 3;
    const int within = chunk * 1024 + threadIdx.x * 4;
    const int pix = b * NPIX + within;
    const int i = within >> 9;
    const int j = within & (WW - 1);
    float4 ov = *(const float4*)(o + pix);

    half4v oh4; half4v uh4; half4v qz;
    float urf[4];
    const float uv[4] = {sigmoidf(ov.x), sigmoidf(ov.y), sigmoidf(ov.z), sigmoidf(ov.w)};
    const float of[4] = {ov.x, ov.y, ov.z, ov.w};
    #pragma unroll
    for (int kk = 0; kk < 4; kk++) {
        oh4[kk] = (h16)of[kk];
        uh4[kk] = (h16)uv[kk];
        urf[kk] = (float)uh4[kk];
        qz[kk]  = (h16)0.f;
    }
    *(half4v*)(u + pix)  = uh4;
    *(half4v*)(q + pix)  = qz;
    *(half4v*)(oh + pix) = oh4;

    const float x = (float)(i + 1);
    float v[6] = {0.f, 0.f, 0.f, 0.f, 0.f, 0.f};
    #pragma unroll
    for (int kk = 0; kk < 4; kk++) {
        const float uu = urf[kk];
        const float y  = (float)(j + 1 + kk);
        v[0] += uu; v[1] += uu * x; v[2] += uu * y;
        v[3] += uu * x * y; v[4] += uu * x * x; v[5] += uu * y * y;
    }
    reduce6_store(v, part0 + ((size_t)b * BLK_PER_BATCH + chunk) * 8);
}

// One fused iteration, fp16 state, NO LDS staging / no mid-kernel barrier.
// Each thread loads its 5x8 u-window (cols jb-2..jb+5) directly from global
// (L1-served redundancy), plus q (3) and o (1). All loads issued at entry.
__global__ __launch_bounds__(256) void step_kernel(const h16* __restrict__ oh,
                                                   const h16* __restrict__ uA,
                                                   const h16* __restrict__ qA,
                                                   h16* __restrict__ uB,
                                                   h16* __restrict__ qB,
                                                   const float* __restrict__ partIn,
                                                   float* __restrict__ partOut,
                                                   float* __restrict__ out,
                                                   int lastFlag) {
    const int b    = blockIdx.x & 7;
    const int tile = blockIdx.x >> 3;
    const int j0 = (tile & 7) * TX;
    const int i0 = (tile >> 3) * TY;
    const h16* ubase = uA + (size_t)b * NPIX;
    const h16* qbase = qA + (size_t)b * NPIX;

    const int lin  = threadIdx.x;
    const int lane = lin & 63;
    const int tx = lin & 15;
    const int ty = lin >> 4;
    const int i  = i0 + ty;
    const int jb = j0 + 4 * tx;
    const int loff = i * WW + jb;
    const size_t goff = (size_t)b * NPIX + loff;

    // ======== entry: issue ALL global loads ========
    // partials: each wave covers all 256 slots of this batch
    float4 pA[4], pB[4];
    #pragma unroll
    for (int s = 0; s < 4; s++) {
        const float* P = partIn + (size_t)b * (BLK_PER_BATCH * 8) + (lane + 64 * s) * 8;
        pA[s] = *(const float4*)P;
        pB[s] = *(const float4*)(P + 4);
    }
    // u window: rows i-2..i+2, cols jb-2..jb+5, per row: half2 | half4 | half2
    const bool lok = (jb > 0);
    const bool rok = (jb + 4 < WW);
    half2v uL[5]; half4v uM[5]; half2v uR[5];
    #pragma unroll
    for (int r = 0; r < 5; r++) {
        const int ii = i - 2 + r;
        const bool rowok = (ii >= 0 && ii < HH);
        half2v l; l[0] = (h16)0.f; l[1] = (h16)0.f;
        half4v m; m[0] = (h16)0.f; m[1] = (h16)0.f; m[2] = (h16)0.f; m[3] = (h16)0.f;
        half2v rr; rr[0] = (h16)0.f; rr[1] = (h16)0.f;
        if (rowok) {
            const h16* rowp = ubase + ii * WW;
            m = *(const half4v*)(rowp + jb);
            if (lok) l  = *(const half2v*)(rowp + jb - 2);
            if (rok) rr = *(const half2v*)(rowp + jb + 4);
        }
        uL[r] = l; uM[r] = m; uR[r] = rr;
    }
    // q / o (clamped addresses)
    const half4v qc4h = *(const half4v*)(qbase + loff);
    const half4v qu4h = *(const half4v*)(qbase + ((i > 0) ? loff - WW : loff));
    const h16    qlh  = qbase[(jb > 0) ? loff - 1 : loff];
    const half4v o4h  = *(const half4v*)(oh + goff);

    // ======== per-wave scalar finalize (butterfly, no LDS / no barrier) ========
    float v6[6] = {0.f, 0.f, 0.f, 0.f, 0.f, 0.f};
    #pragma unroll
    for (int s = 0; s < 4; s++) {
        v6[0] += pA[s].x; v6[1] += pA[s].y; v6[2] += pA[s].z;
        v6[3] += pA[s].w; v6[4] += pB[s].x; v6[5] += pB[s].y;
    }
    #pragma unroll
    for (int mask = 1; mask < 64; mask <<= 1) {
        #pragma unroll
        for (int c = 0; c < 6; c++) v6[c] += __shfl_xor(v6[c], mask, 64);
    }
    const double sS  = (double)v6[0];
    const double inv = 1.0 / sS;
    const double cxd = (double)v6[1] * inv;
    const double cyd = (double)v6[2] * inv;
    const float cxf    = (float)cxd;
    const float cyf    = (float)cyd;
    const float cossin = (float)((double)v6[3] * inv - cxd * cyd);
    const float bsin   = (float)((double)v6[4] * inv - cxd * cxd);
    const float asin_  = (float)((double)v6[5] * inv - cyd * cyd);

    // ======== convert u window to fp32: U[r][c] = u(i-2+r, jb-2+c), c=0..7 ========
    float U[5][8];
    #pragma unroll
    for (int r = 0; r < 5; r++) {
        U[r][0] = (float)uL[r][0]; U[r][1] = (float)uL[r][1];
        U[r][2] = (float)uM[r][0]; U[r][3] = (float)uM[r][1];
        U[r][4] = (float)uM[r][2]; U[r][5] = (float)uM[r][3];
        U[r][6] = (float)uR[r][0]; U[r][7] = (float)uR[r][1];
    }

    // ======== conv: v-pass then h-pass (col jb+k ↔ index k+2) ========
    float vs[8];
    #pragma unroll
    for (int c = 0; c < 8; c++)
        vs[c] = W0f * U[0][c] + W1f * U[1][c] + U[2][c] + W1f * U[3][c] + W0f * U[4][c];
    const float Ri = edge1d(i);
    float p4[4];
    #pragma unroll
    for (int k = 0; k < 4; k++) {
        const float convU = W0f * vs[k] + W1f * vs[k + 1] + vs[k + 2]
                          + W1f * vs[k + 3] + W0f * vs[k + 4];
        p4[k] = INV_NORM * (Ri * edge1d(jb + k) - 2.0f * convU);
    }

    const float dx  = (float)(i + 1) - cxf;
    const float dxu = (float)i - cxf;
    const float qcv[4] = {(float)qc4h[0], (float)qc4h[1], (float)qc4h[2], (float)qc4h[3]};
    const float quv[4] = {(float)qu4h[0], (float)qu4h[1], (float)qu4h[2], (float)qu4h[3]};
    const float ov4[4] = {(float)o4h[0], (float)o4h[1], (float)o4h[2], (float)o4h[3]};
    const float qlv = (float)qlh;

    float a_c[4], b_c[4], qn[4], a_u[4];
    #pragma unroll
    for (int k = 0; k < 4; k++) {
        const float dy = (float)(jb + k + 1) - cyf;
        evalF(U[2][k + 2], U[3][k + 2], U[2][k + 3], qcv[k],
              dx, dy, cossin, bsin, asin_, a_c[k], b_c[k], qn[k]);
        float au, bu_d, qu_d;
        evalF(U[1][k + 2], U[2][k + 2], U[1][k + 3], quv[k],
              dxu, dy, cossin, bsin, asin_, au, bu_d, qu_d);
        a_u[k] = (i > 0) ? au : 0.f;
    }
    float b_l = 0.f;
    {
        float al_d, bl, ql_d;
        evalF(U[2][1], U[3][1], U[2][2], qlv,
              dx, (float)jb - cyf, cossin, bsin, asin_, al_d, bl, ql_d);
        b_l = (jb > 0) ? bl : 0.f;
    }

    float un4[4], t4[4];
    #pragma unroll
    for (int k = 0; k < 4; k++) {
        const float bleft = (k == 0) ? b_l : b_c[k - 1];
        const float Tq = a_c[k] + b_c[k] - a_u[k] - bleft;
        t4[k]  = ov4[k] - p4[k] - Tq;
        un4[k] = sigmoidf(t4[k]);
    }

    // round state to fp16; sums use the ROUNDED u for field consistency
    half4v uh4, qh4;
    float urf[4];
    #pragma unroll
    for (int k = 0; k < 4; k++) {
        uh4[k] = (h16)un4[k];
        urf[k] = (float)uh4[k];
        qh4[k] = (h16)qn[k];
    }
    *(half4v*)(uB + goff) = uh4;
    *(half4v*)(qB + goff) = qh4;
    if (lastFlag) *(float4*)(out + goff) = make_float4(t4[0], t4[1], t4[2], t4[3]);

    const float x = (float)(i + 1);
    float s0 = 0.f, sy = 0.f, syy = 0.f;
    #pragma unroll
    for (int k = 0; k < 4; k++) {
        const float y = (float)(jb + k + 1);
        s0 += urf[k]; sy += urf[k] * y; syy += urf[k] * y * y;
    }
    float v[6] = {s0, x * s0, sy, x * sy, x * x * s0, syy};
    reduce6_store(v, partOut + ((size_t)b * BLK_PER_BATCH + tile) * 8);
}

extern "C" void kernel_launch(void* const* d_in, const int* in_sizes, int n_in,
                              void* d_out, int out_size, void* d_ws, size_t ws_size,
                              hipStream_t stream) {
    const float* o = (const float*)d_in[0];
    float* out = (float*)d_out;

    h16* uA = (h16*)d_ws;
    h16* uB = uA + (size_t)NTOT;
    h16* qA = uB + (size_t)NTOT;
    h16* qB = qA + (size_t)NTOT;
    h16* oh = qB + (size_t)NTOT;
    float* partials = (float*)(oh + (size_t)NTOT);   // 51 iters * 16384 floats

    init_kernel<<<2048, 256, 0, stream>>>(o, uA, qA, oh, partials);

    h16 *ua = uA, *ub = uB, *qa = qA, *qb = qB;
    for (int k = 0; k < ITER; k++) {
        step_kernel<<<2048, 256, 0, stream>>>(
            oh, ua, qa, ub, qb,
            partials + (size_t)k * PART_ITER_STRIDE,
            partials + (size_t)(k + 1) * PART_ITER_STRIDE,
            out, (k == ITER - 1) ? 1 : 0);
        h16* tmp;
        tmp = ua; ua = ub; ub = tmp;
        tmp = qa; qa = qb; qb = tmp;
    }
}